// Round 5
// baseline (1118.708 us; speedup 1.0000x reference)
//
#include <hip/hip_runtime.h>
#include <cmath>

#define NT 256

// ---- problem constants (DEPTH=18, N_ARY=2, H=128, X=128) ----
#define NTOT   262143     // 2^18 - 1
#define NINT   131071     // internal nodes: ids 0 .. 131070
#define LEAF0  131071
#define NLEAF  131072

// ws layout (floats)
#define WHC_OFF  0                         // [NINT][128]  (bias included)
#define WF_OFF   (NINT * 128)              // [NINT][128]  (bias included)
#define WWT_OFF  (2 * NINT * 128)          // [128][256]  WwT[k][j] = Ww[j][k]
#define UFT_OFF  (WWT_OFF + 128 * 256)     // [256][128]  UfT[k][j] = Uf[j][k]
#define UHCT_OFF (UFT_OFF + 256 * 128)     // [256][128]
#define WS_FLOATS (UHCT_OFF + 256 * 128)
#define WS_BYTES  ((size_t)WS_FLOATS * 4)  // ~134.6 MB

__device__ __forceinline__ float sigmoid_(float v) {
    return 1.0f / (1.0f + expf(-v));
}

// =================== weight transpose ===================

__global__ __launch_bounds__(NT) void transpose_weights(
    const float* __restrict__ Ww, const float* __restrict__ Uf,
    const float* __restrict__ Uhc, float* __restrict__ ws)
{
    int t = blockIdx.x * NT + threadIdx.x;
    if (t < 128 * 256) {                 // WwT
        int k = t >> 8, j = t & 255;
        ws[WWT_OFF + t] = Ww[j * 128 + k];
    } else if (t < 2 * 32768) {          // UfT
        int u = t - 32768;
        int k = u >> 7, j = u & 127;
        ws[UFT_OFF + u] = Uf[j * 256 + k];
    } else if (t < 3 * 32768) {          // UhcT
        int u = t - 2 * 32768;
        int k = u >> 7, j = u & 127;
        ws[UHCT_OFF + u] = Uhc[j * 256 + k];
    }
}

// =================== wx for ALL nodes (+ leaf h fused) ===================
// 64 nodes/block, 256 threads. lane = tid&63 covers all 256 output features
// (no duplicate weight addresses); wq = tid>>6 owns 16 nodes.
__global__ __launch_bounds__(NT) void wx_all(
    const float* __restrict__ x, const float* __restrict__ ws_all,
    const float* __restrict__ Wb, float* __restrict__ ws, float* __restrict__ h)
{
    __shared__ __align__(16) float sX[64 * 128];   // 32 KB
    const float* wwt = ws_all + WWT_OFF;
    const int tid = threadIdx.x;
    const int nbase = blockIdx.x * 64;
    const int nb = min(64, NTOT - nbase);

    const int lane = tid & 63;
    const int j0 = lane << 2;          // 0..252  (j<128: hc-half, j>=128: f-half)
    const int i0 = (tid >> 6) << 4;    // 0,16,32,48

    {
        const float4* xg = (const float4*)(x + (size_t)nbase * 128);
        float4* sX4 = (float4*)sX;
        for (int idx = tid; idx < nb * 32; idx += NT) sX4[idx] = xg[idx];
    }
    __syncthreads();

    float acc[16][4];
#pragma unroll
    for (int i = 0; i < 16; ++i)
#pragma unroll
        for (int j = 0; j < 4; ++j) acc[i][j] = 0.f;

    const float4* sX4 = (const float4*)sX;
    for (int k0 = 0; k0 < 128; k0 += 8) {
        float4 w[8];
#pragma unroll
        for (int u = 0; u < 8; ++u)
            w[u] = *(const float4*)&wwt[(size_t)(k0 + u) * 256 + j0];
#pragma unroll
        for (int i = 0; i < 16; ++i) {
            float4 a0 = sX4[(i0 + i) * 32 + (k0 >> 2)];       // broadcast reads
            float4 a1 = sX4[(i0 + i) * 32 + (k0 >> 2) + 1];
            const float* ap0 = (const float*)&a0;
            const float* ap1 = (const float*)&a1;
#pragma unroll
            for (int u = 0; u < 8; ++u) {
                float av = (u < 4) ? ap0[u] : ap1[u - 4];
                const float* wp = (const float*)&w[u];
#pragma unroll
                for (int j = 0; j < 4; ++j)
                    acc[i][j] = fmaf(wp[j], av, acc[i][j]);
            }
        }
    }

    float4 bj = *(const float4*)&Wb[j0];
    const float* bp = (const float*)&bj;
    float* whcw = ws + WHC_OFF;
    float* wfw  = ws + WF_OFF;
    const bool isF = (lane >= 32);

#pragma unroll
    for (int i = 0; i < 16; ++i) {
        int node = nbase + i0 + i;
        if (node >= NTOT) continue;            // wave-uniform
        float4 o4;
        float* o = (float*)&o4;
#pragma unroll
        for (int j = 0; j < 4; ++j) o[j] = acc[i][j] + bp[j];
        if (node < NINT) {                     // wave-uniform per i
            float* dst = isF ? (wfw + (size_t)node * 128 + (j0 - 128))
                             : (whcw + (size_t)node * 128 + j0);
            *(float4*)dst = o4;
        } else {
            // leaf: lane l<32 holds whc[j0..], lane l+32 holds wf[j0-128..]
            float p[4];
#pragma unroll
            for (int j = 0; j < 4; ++j) p[j] = __shfl_xor(o[j], 32, 64);
            if (!isF) {
                float4 r;
                float* rp = (float*)&r;
#pragma unroll
                for (int j = 0; j < 4; ++j) {
                    float f = sigmoid_(p[j]);
                    rp[j] = (1.0f - f) * tanhf(o[j]);
                }
                *(float4*)&h[(size_t)node * 128 + j0] = r;
            }
        }
    }
}

// =================== internal level (size >= 64, multiple of 64) ===================
// 64 nodes/block, 256 threads; jq covers 128 outputs, iq owns 8 nodes.
__global__ __launch_bounds__(NT) void level_kernel(
    const float* __restrict__ ws_all, float* __restrict__ h, int start)
{
    __shared__ __align__(16) float sH[64 * 256];   // 64 KB
    const float* uft  = ws_all + UFT_OFF;
    const float* uhct = ws_all + UHCT_OFF;
    const float* whcw = ws_all + WHC_OFF;
    const float* wfw  = ws_all + WF_OFF;

    const int tid = threadIdx.x;
    const int s0 = start + blockIdx.x * 64;

    const int jq = tid & 31;  const int j0 = jq << 2;
    const int iq = tid >> 5;  const int i0 = iq << 3;   // 0..56

    {
        const float4* hg = (const float4*)(h + ((size_t)2 * s0 + 1) * 128);
        float4* sH4 = (float4*)sH;
        for (int idx = tid; idx < 64 * 64; idx += NT) sH4[idx] = hg[idx];
    }
    __syncthreads();

    const float4* sH4 = (const float4*)sH;

    // ---- P2: f = sigmoid(Uf @ hcat + wf) ----
    float fv[8][4];
#pragma unroll
    for (int i = 0; i < 8; ++i)
#pragma unroll
        for (int j = 0; j < 4; ++j) fv[i][j] = 0.f;

    for (int k0 = 0; k0 < 256; k0 += 8) {
        float4 w[8];
#pragma unroll
        for (int u = 0; u < 8; ++u)
            w[u] = *(const float4*)&uft[(size_t)(k0 + u) * 128 + j0];
#pragma unroll
        for (int i = 0; i < 8; ++i) {
            float4 a0 = sH4[(i0 + i) * 64 + (k0 >> 2)];
            float4 a1 = sH4[(i0 + i) * 64 + (k0 >> 2) + 1];
            const float* ap0 = (const float*)&a0;
            const float* ap1 = (const float*)&a1;
#pragma unroll
            for (int u = 0; u < 8; ++u) {
                float av = (u < 4) ? ap0[u] : ap1[u - 4];
                const float* wp = (const float*)&w[u];
#pragma unroll
                for (int j = 0; j < 4; ++j)
                    fv[i][j] = fmaf(wp[j], av, fv[i][j]);
            }
        }
    }
#pragma unroll
    for (int i = 0; i < 8; ++i) {
        float4 wfv = *(const float4*)&wfw[(size_t)(s0 + i0 + i) * 128 + j0];
        const float* wfp = (const float*)&wfv;
#pragma unroll
        for (int j = 0; j < 4; ++j)
            fv[i][j] = sigmoid_(fv[i][j] + wfp[j]);
    }

    __syncthreads();   // all P2 reads of sH done

    // ---- hsum (regs) + scale hcat in place by f_rep ----
    float hs[8][4];
#pragma unroll
    for (int i = 0; i < 8; ++i) {
        float4* row = (float4*)&sH[(i0 + i) * 256];
        float4 c0 = row[jq];
        float4 c1 = row[32 + jq];
        hs[i][0] = c0.x + c1.x;
        hs[i][1] = c0.y + c1.y;
        hs[i][2] = c0.z + c1.z;
        hs[i][3] = c0.w + c1.w;
        c0.x *= fv[i][0]; c0.y *= fv[i][1]; c0.z *= fv[i][2]; c0.w *= fv[i][3];
        c1.x *= fv[i][0]; c1.y *= fv[i][1]; c1.z *= fv[i][2]; c1.w *= fv[i][3];
        row[jq] = c0;
        row[32 + jq] = c1;
    }
    __syncthreads();

    // ---- P3: cand = Uhc @ (f_rep * hcat) ----
    float cv[8][4];
#pragma unroll
    for (int i = 0; i < 8; ++i)
#pragma unroll
        for (int j = 0; j < 4; ++j) cv[i][j] = 0.f;

    for (int k0 = 0; k0 < 256; k0 += 8) {
        float4 w[8];
#pragma unroll
        for (int u = 0; u < 8; ++u)
            w[u] = *(const float4*)&uhct[(size_t)(k0 + u) * 128 + j0];
#pragma unroll
        for (int i = 0; i < 8; ++i) {
            float4 a0 = sH4[(i0 + i) * 64 + (k0 >> 2)];
            float4 a1 = sH4[(i0 + i) * 64 + (k0 >> 2) + 1];
            const float* ap0 = (const float*)&a0;
            const float* ap1 = (const float*)&a1;
#pragma unroll
            for (int u = 0; u < 8; ++u) {
                float av = (u < 4) ? ap0[u] : ap1[u - 4];
                const float* wp = (const float*)&w[u];
#pragma unroll
                for (int j = 0; j < 4; ++j)
                    cv[i][j] = fmaf(wp[j], av, cv[i][j]);
            }
        }
    }

    // ---- epilogue: h = f*hsum + (1-f)*tanh(cand + whc) ----
#pragma unroll
    for (int i = 0; i < 8; ++i) {
        float4 whcv = *(const float4*)&whcw[(size_t)(s0 + i0 + i) * 128 + j0];
        const float* wp = (const float*)&whcv;
        float4 o;
        float* op = (float*)&o;
#pragma unroll
        for (int j = 0; j < 4; ++j) {
            float t = tanhf(cv[i][j] + wp[j]);
            op[j] = fv[i][j] * hs[i][j] + (1.0f - fv[i][j]) * t;
        }
        *(float4*)&h[(size_t)(s0 + i0 + i) * 128 + j0] = o;
    }
}

// =================== tail: levels 5..0 in one block ===================
__global__ __launch_bounds__(NT) void tail_kernel(
    const float* __restrict__ ws_all, float* __restrict__ h)
{
    __shared__ __align__(16) float bufA[64 * 128];   // 32 KB
    __shared__ __align__(16) float bufB[32 * 128];   // 16 KB
    __shared__ __align__(16) float sF[8 * 128];      // 4 KB
    const float* uft  = ws_all + UFT_OFF;
    const float* uhct = ws_all + UHCT_OFF;
    const float* whcw = ws_all + WHC_OFF;
    const float* wfw  = ws_all + WF_OFF;

    const int tid = threadIdx.x;
    const int jq = tid & 31;  const int j0 = jq << 2;
    const int iq = tid >> 5;               // 0..7 (node group)

    // load level-6 h (nodes 63..126, 64 nodes)
    {
        const float4* hg = (const float4*)(h + (size_t)63 * 128);
        float4* b4 = (float4*)bufA;
        for (int idx = tid; idx < 64 * 32; idx += NT) b4[idx] = hg[idx];
    }
    __syncthreads();

    float* child = bufA;
    float* cur   = bufB;

    for (int lvl = 5; lvl >= 0; --lvl) {
        const int start = (1 << lvl) - 1;
        const int size  = 1 << lvl;
        for (int pass = 0; pass < size; pass += 8) {
            const int ni = pass + iq;
            const bool act = (ni < size);
            float f[4] = {0.f, 0.f, 0.f, 0.f};
            if (act) {
                const float* hc = child + ni * 256;
                float fv[4] = {0.f, 0.f, 0.f, 0.f};
                for (int k = 0; k < 256; k += 4) {
#pragma unroll
                    for (int u = 0; u < 4; ++u) {
                        float av = hc[k + u];
                        float4 w = *(const float4*)&uft[(size_t)(k + u) * 128 + j0];
                        fv[0] = fmaf(w.x, av, fv[0]);
                        fv[1] = fmaf(w.y, av, fv[1]);
                        fv[2] = fmaf(w.z, av, fv[2]);
                        fv[3] = fmaf(w.w, av, fv[3]);
                    }
                }
                const int gn = start + ni;
                float4 wfv = *(const float4*)&wfw[(size_t)gn * 128 + j0];
                const float* wfp = (const float*)&wfv;
#pragma unroll
                for (int j = 0; j < 4; ++j) {
                    f[j] = sigmoid_(fv[j] + wfp[j]);
                    sF[iq * 128 + j0 + j] = f[j];
                }
            }
            __syncthreads();
            if (act) {
                const float* hc = child + ni * 256;
                const float* fr = sF + iq * 128;
                float cv[4] = {0.f, 0.f, 0.f, 0.f};
                for (int k = 0; k < 256; k += 4) {
#pragma unroll
                    for (int u = 0; u < 4; ++u) {
                        float av = hc[k + u] * fr[(k + u) & 127];
                        float4 w = *(const float4*)&uhct[(size_t)(k + u) * 128 + j0];
                        cv[0] = fmaf(w.x, av, cv[0]);
                        cv[1] = fmaf(w.y, av, cv[1]);
                        cv[2] = fmaf(w.z, av, cv[2]);
                        cv[3] = fmaf(w.w, av, cv[3]);
                    }
                }
                const int gn = start + ni;
                float4 whcv = *(const float4*)&whcw[(size_t)gn * 128 + j0];
                const float* wp = (const float*)&whcv;
                float4 o;
                float* op = (float*)&o;
#pragma unroll
                for (int j = 0; j < 4; ++j) {
                    float hsum = hc[j0 + j] + hc[128 + j0 + j];
                    float t = tanhf(cv[j] + wp[j]);
                    op[j] = f[j] * hsum + (1.0f - f[j]) * t;
                }
                *(float4*)&cur[ni * 128 + j0] = o;
                *(float4*)&h[(size_t)gn * 128 + j0] = o;
            }
            __syncthreads();
        }
        float* t = child; child = cur; cur = t;
    }
}

// =================== fallback path (no workspace) ===================

__global__ __launch_bounds__(NT) void fb_leaf(
    const float* __restrict__ x, const float* __restrict__ Ww,
    const float* __restrict__ Wb, float* __restrict__ h, int start, int size)
{
    __shared__ float sA[32 * 128];
    __shared__ float sW[16 * 260];
    const int tid = threadIdx.x;
    const int nbase = blockIdx.x * 32;
    const int s0 = start + nbase;
    const int nb = min(32, size - nbase);
    const int jq = tid & 31, iq = tid >> 5;
    const int j0 = jq << 2, i0 = iq << 2;
    {
        const float4* xg = (const float4*)(x + (size_t)s0 * 128);
        float4* sA4 = (float4*)sA;
        for (int idx = tid; idx < nb * 32; idx += NT) sA4[idx] = xg[idx];
    }
    float whc[4][4], wf[4][4];
#pragma unroll
    for (int j = 0; j < 4; ++j)
#pragma unroll
        for (int i = 0; i < 4; ++i) { whc[j][i] = 0.f; wf[j][i] = 0.f; }
    for (int k0 = 0; k0 < 128; k0 += 16) {
        __syncthreads();
        const float4* Wg = (const float4*)Ww;
        for (int idx = tid; idx < 256 * 4; idx += NT) {
            int j2 = idx >> 2, kq = idx & 3;
            float4 v = Wg[j2 * 32 + (k0 >> 2) + kq];
            int kb = kq << 2;
            sW[(kb + 0) * 260 + j2] = v.x; sW[(kb + 1) * 260 + j2] = v.y;
            sW[(kb + 2) * 260 + j2] = v.z; sW[(kb + 3) * 260 + j2] = v.w;
        }
        __syncthreads();
#pragma unroll
        for (int kk = 0; kk < 16; kk += 4) {
            float4 a4[4];
#pragma unroll
            for (int i = 0; i < 4; ++i)
                a4[i] = ((const float4*)sA)[(i0 + i) * 32 + ((k0 + kk) >> 2)];
#pragma unroll
            for (int u = 0; u < 4; ++u) {
                int k = kk + u;
                float4 w0 = *((const float4*)&sW[k * 260 + j0]);
                float4 w1 = *((const float4*)&sW[k * 260 + 128 + j0]);
                const float* w0p = (const float*)&w0;
                const float* w1p = (const float*)&w1;
#pragma unroll
                for (int i = 0; i < 4; ++i) {
                    float av = ((const float*)&a4[i])[u];
#pragma unroll
                    for (int j = 0; j < 4; ++j) {
                        whc[j][i] = fmaf(w0p[j], av, whc[j][i]);
                        wf[j][i]  = fmaf(w1p[j], av, wf[j][i]);
                    }
                }
            }
        }
    }
#pragma unroll
    for (int i = 0; i < 4; ++i) {
        if (i0 + i < nb) {
            float4 o; float* op = (float*)&o;
#pragma unroll
            for (int j = 0; j < 4; ++j) {
                float f = sigmoid_(wf[j][i] + Wb[128 + j0 + j]);
                op[j] = (1.0f - f) * tanhf(whc[j][i] + Wb[j0 + j]);
            }
            *(float4*)&h[((size_t)(s0 + i0 + i)) * 128 + j0] = o;
        }
    }
}

__global__ __launch_bounds__(NT) void fb_internal(
    const float* __restrict__ x, const float* __restrict__ Ww,
    const float* __restrict__ Wb, const float* __restrict__ Uf,
    const float* __restrict__ Uhc, float* __restrict__ h, int start, int size)
{
    __shared__ float sA[32 * 256];
    __shared__ float sW[4224];
    const int tid = threadIdx.x;
    const int nbase = blockIdx.x * 32;
    const int s0 = start + nbase;
    const int nb = min(32, size - nbase);
    const int jq = tid & 31, iq = tid >> 5;
    const int j0 = jq << 2, i0 = iq << 2;
    {
        const float4* xg = (const float4*)(x + (size_t)s0 * 128);
        float4* sA4 = (float4*)sA;
        for (int idx = tid; idx < nb * 32; idx += NT) sA4[idx] = xg[idx];
    }
    float whc[4][4], wf[4][4];
#pragma unroll
    for (int j = 0; j < 4; ++j)
#pragma unroll
        for (int i = 0; i < 4; ++i) { whc[j][i] = 0.f; wf[j][i] = 0.f; }
    for (int k0 = 0; k0 < 128; k0 += 16) {
        __syncthreads();
        const float4* Wg = (const float4*)Ww;
        for (int idx = tid; idx < 256 * 4; idx += NT) {
            int j2 = idx >> 2, kq = idx & 3;
            float4 v = Wg[j2 * 32 + (k0 >> 2) + kq];
            int kb = kq << 2;
            sW[(kb + 0) * 260 + j2] = v.x; sW[(kb + 1) * 260 + j2] = v.y;
            sW[(kb + 2) * 260 + j2] = v.z; sW[(kb + 3) * 260 + j2] = v.w;
        }
        __syncthreads();
#pragma unroll
        for (int kk = 0; kk < 16; kk += 4) {
            float4 a4[4];
#pragma unroll
            for (int i = 0; i < 4; ++i)
                a4[i] = ((const float4*)sA)[(i0 + i) * 32 + ((k0 + kk) >> 2)];
#pragma unroll
            for (int u = 0; u < 4; ++u) {
                int k = kk + u;
                float4 w0 = *((const float4*)&sW[k * 260 + j0]);
                float4 w1 = *((const float4*)&sW[k * 260 + 128 + j0]);
                const float* w0p = (const float*)&w0;
                const float* w1p = (const float*)&w1;
#pragma unroll
                for (int i = 0; i < 4; ++i) {
                    float av = ((const float*)&a4[i])[u];
#pragma unroll
                    for (int j = 0; j < 4; ++j) {
                        whc[j][i] = fmaf(w0p[j], av, whc[j][i]);
                        wf[j][i]  = fmaf(w1p[j], av, wf[j][i]);
                    }
                }
            }
        }
    }
#pragma unroll
    for (int j = 0; j < 4; ++j) {
        float bhc = Wb[j0 + j], bf = Wb[128 + j0 + j];
#pragma unroll
        for (int i = 0; i < 4; ++i) { whc[j][i] += bhc; wf[j][i] += bf; }
    }
    __syncthreads();
    {
        const float4* hg = (const float4*)(h + ((size_t)2 * s0 + 1) * 128);
        float4* sA4 = (float4*)sA;
        for (int idx = tid; idx < nb * 64; idx += NT) sA4[idx] = hg[idx];
    }
    float fv[4][4];
#pragma unroll
    for (int j = 0; j < 4; ++j)
#pragma unroll
        for (int i = 0; i < 4; ++i) fv[j][i] = 0.f;
    for (int k0 = 0; k0 < 256; k0 += 32) {
        __syncthreads();
        const float4* Ug = (const float4*)Uf;
        for (int idx = tid; idx < 128 * 8; idx += NT) {
            int j2 = idx >> 3, kq = idx & 7;
            float4 v = Ug[j2 * 64 + (k0 >> 2) + kq];
            int kb = kq << 2;
            sW[(kb + 0) * 132 + j2] = v.x; sW[(kb + 1) * 132 + j2] = v.y;
            sW[(kb + 2) * 132 + j2] = v.z; sW[(kb + 3) * 132 + j2] = v.w;
        }
        __syncthreads();
#pragma unroll
        for (int kk = 0; kk < 32; kk += 4) {
            float4 a4[4];
#pragma unroll
            for (int i = 0; i < 4; ++i)
                a4[i] = ((const float4*)sA)[(i0 + i) * 64 + ((k0 + kk) >> 2)];
#pragma unroll
            for (int u = 0; u < 4; ++u) {
                int k = kk + u;
                float4 w = *((const float4*)&sW[k * 132 + j0]);
                const float* wp = (const float*)&w;
#pragma unroll
                for (int i = 0; i < 4; ++i) {
                    float av = ((const float*)&a4[i])[u];
#pragma unroll
                    for (int j = 0; j < 4; ++j)
                        fv[j][i] = fmaf(wp[j], av, fv[j][i]);
                }
            }
        }
    }
#pragma unroll
    for (int j = 0; j < 4; ++j)
#pragma unroll
        for (int i = 0; i < 4; ++i)
            fv[j][i] = sigmoid_(fv[j][i] + wf[j][i]);
    __syncthreads();
    float hs[4][4];
#pragma unroll
    for (int i = 0; i < 4; ++i) {
        float4* row = (float4*)&sA[(i0 + i) * 256];
        float4 c0 = row[jq], c1 = row[32 + jq];
        hs[0][i] = c0.x + c1.x; hs[1][i] = c0.y + c1.y;
        hs[2][i] = c0.z + c1.z; hs[3][i] = c0.w + c1.w;
        c0.x *= fv[0][i]; c0.y *= fv[1][i]; c0.z *= fv[2][i]; c0.w *= fv[3][i];
        c1.x *= fv[0][i]; c1.y *= fv[1][i]; c1.z *= fv[2][i]; c1.w *= fv[3][i];
        row[jq] = c0; row[32 + jq] = c1;
    }
    float cv[4][4];
#pragma unroll
    for (int j = 0; j < 4; ++j)
#pragma unroll
        for (int i = 0; i < 4; ++i) cv[j][i] = 0.f;
    for (int k0 = 0; k0 < 256; k0 += 32) {
        __syncthreads();
        const float4* Ug = (const float4*)Uhc;
        for (int idx = tid; idx < 128 * 8; idx += NT) {
            int j2 = idx >> 3, kq = idx & 7;
            float4 v = Ug[j2 * 64 + (k0 >> 2) + kq];
            int kb = kq << 2;
            sW[(kb + 0) * 132 + j2] = v.x; sW[(kb + 1) * 132 + j2] = v.y;
            sW[(kb + 2) * 132 + j2] = v.z; sW[(kb + 3) * 132 + j2] = v.w;
        }
        __syncthreads();
#pragma unroll
        for (int kk = 0; kk < 32; kk += 4) {
            float4 a4[4];
#pragma unroll
            for (int i = 0; i < 4; ++i)
                a4[i] = ((const float4*)sA)[(i0 + i) * 64 + ((k0 + kk) >> 2)];
#pragma unroll
            for (int u = 0; u < 4; ++u) {
                int k = kk + u;
                float4 w = *((const float4*)&sW[k * 132 + j0]);
                const float* wp = (const float*)&w;
#pragma unroll
                for (int i = 0; i < 4; ++i) {
                    float av = ((const float*)&a4[i])[u];
#pragma unroll
                    for (int j = 0; j < 4; ++j)
                        cv[j][i] = fmaf(wp[j], av, cv[j][i]);
                }
            }
        }
    }
#pragma unroll
    for (int i = 0; i < 4; ++i) {
        if (i0 + i < nb) {
            float4 o; float* op = (float*)&o;
#pragma unroll
            for (int j = 0; j < 4; ++j) {
                float t = tanhf(cv[j][i] + whc[j][i]);
                op[j] = fv[j][i] * hs[j][i] + (1.0f - fv[j][i]) * t;
            }
            *(float4*)&h[((size_t)(s0 + i0 + i)) * 128 + j0] = o;
        }
    }
}

// =================== launcher ===================

extern "C" void kernel_launch(void* const* d_in, const int* in_sizes, int n_in,
                              void* d_out, int out_size, void* d_ws, size_t ws_size,
                              hipStream_t stream)
{
    (void)in_sizes; (void)n_in; (void)out_size;
    const float* x   = (const float*)d_in[0];
    const float* Ww  = (const float*)d_in[1];
    const float* Wb  = (const float*)d_in[2];
    const float* Uf  = (const float*)d_in[3];
    const float* Uhc = (const float*)d_in[4];
    float* h = (float*)d_out;
    const int depth = 18;

    if (ws_size >= WS_BYTES) {
        float* ws = (float*)d_ws;
        transpose_weights<<<(3 * 32768 + NT - 1) / NT, NT, 0, stream>>>(Ww, Uf, Uhc, ws);
        wx_all<<<(NTOT + 63) / 64, NT, 0, stream>>>(x, ws, Wb, ws, h);
        for (int lvl = 16; lvl >= 6; --lvl) {
            int start = (1 << lvl) - 1;
            int size  = 1 << lvl;
            level_kernel<<<size / 64, NT, 0, stream>>>(ws, h, start);
        }
        tail_kernel<<<1, NT, 0, stream>>>(ws, h);
    } else {
        {
            int lvl = depth - 1;
            int start = (1 << lvl) - 1, size = 1 << lvl;
            fb_leaf<<<(size + 31) / 32, NT, 0, stream>>>(x, Ww, Wb, h, start, size);
        }
        for (int lvl = depth - 2; lvl >= 0; --lvl) {
            int start = (1 << lvl) - 1, size = 1 << lvl;
            fb_internal<<<(size + 31) / 32, NT, 0, stream>>>(x, Ww, Wb, Uf, Uhc, h, start, size);
        }
    }
}